// Round 1
// baseline (343.506 us; speedup 1.0000x reference)
//
#include <hip/hip_runtime.h>
#include <hip/hip_bf16.h>
#include <math.h>

// Problem: B=4, N=40962, K=7, C=128
//   sig[b,m]   = sigmoid( sum_d tanh((query[b,m,:]@W1)[d] + b1[d]) * V[d] + bV )
//   score[b,n,k] = sig[b, neigh[n,k]]
//   attn = score / sum_k score
//   context[b,n,:] = sum_k attn[b,n,k] * values[b, neigh[n,k], :]

#define CDIM 128
#define KNEIGH 7
#define ROWS 64     // rows per block in kernel 1
#define CCH 32      // c-chunk for LDS staging

// ---------------- Kernel 1: per-row score precompute -----------------------
// Tiled fp32 GEMM (rows x 128) @ (128 x 128) with fused tanh/dot-V/sigmoid
// epilogue. Thread register tile: 4 rows x 8 cols. Block 256 threads, 64 rows.
__global__ __launch_bounds__(256) void k1_row_scores(
    const float* __restrict__ query,   // (totalRows, 128)
    const float* __restrict__ W1,      // (128, 128) row-major [c][d]
    const float* __restrict__ b1,      // (128)
    const float* __restrict__ V,       // (128)
    const float* __restrict__ bV,      // (1)
    float* __restrict__ sig,           // (totalRows)
    int totalRows)
{
    __shared__ float Wc[CCH][CDIM];       // 16 KB: W1 chunk  [c_local][d]
    __shared__ float Qc[ROWS][CCH + 1];   // ~8.4 KB: query chunk, padded (+1 -> 2-way max)
    __shared__ float red[ROWS][17];       // ~4.4 KB: cross-cg reduction

    const int t  = threadIdx.x;
    const int rg = t & 15;    // 16 row-groups of 4 rows
    const int cg = t >> 4;    // 16 col-groups of 8 cols
    const int rowBase = blockIdx.x * ROWS;
    const int d0 = cg * 8;

    float vv[8], bb[8];
#pragma unroll
    for (int j = 0; j < 8; ++j) { vv[j] = V[d0 + j]; bb[j] = b1[d0 + j]; }

    float acc[4][8];
#pragma unroll
    for (int i = 0; i < 4; ++i)
#pragma unroll
        for (int j = 0; j < 8; ++j) acc[i][j] = bb[j];   // fold b1 into init

    for (int ch = 0; ch < CDIM / CCH; ++ch) {
        __syncthreads();
        // stage W1 chunk: 32x128 floats, coalesced float4
#pragma unroll
        for (int v = 0; v < 4; ++v) {
            int flat = (v * 256 + t) * 4;          // 0..16380
            int r  = flat >> 7;                    // 0..31
            int c0 = flat & 127;
            float4 w4 = *(const float4*)(W1 + (size_t)(ch * CCH + r) * CDIM + c0);
            *(float4*)(&Wc[r][c0]) = w4;
        }
        // stage query chunk: 64 rows x 32 floats
#pragma unroll
        for (int v = 0; v < 2; ++v) {
            int flat = (v * 256 + t) * 4;          // 0..8188 covering 2048 floats
            int r  = flat >> 5;                    // 0..63
            int c0 = flat & 31;
            int gr = rowBase + r;
            float4 q4 = make_float4(0.f, 0.f, 0.f, 0.f);
            if (gr < totalRows)
                q4 = *(const float4*)(query + (size_t)gr * CDIM + ch * CCH + c0);
            Qc[r][c0 + 0] = q4.x; Qc[r][c0 + 1] = q4.y;
            Qc[r][c0 + 2] = q4.z; Qc[r][c0 + 3] = q4.w;
        }
        __syncthreads();

#pragma unroll
        for (int cc = 0; cc < CCH; ++cc) {
            float4 wa = *(const float4*)(&Wc[cc][d0]);
            float4 wb = *(const float4*)(&Wc[cc][d0 + 4]);
            float q0 = Qc[rg * 4 + 0][cc];
            float q1 = Qc[rg * 4 + 1][cc];
            float q2 = Qc[rg * 4 + 2][cc];
            float q3 = Qc[rg * 4 + 3][cc];
            acc[0][0] += q0 * wa.x; acc[0][1] += q0 * wa.y; acc[0][2] += q0 * wa.z; acc[0][3] += q0 * wa.w;
            acc[0][4] += q0 * wb.x; acc[0][5] += q0 * wb.y; acc[0][6] += q0 * wb.z; acc[0][7] += q0 * wb.w;
            acc[1][0] += q1 * wa.x; acc[1][1] += q1 * wa.y; acc[1][2] += q1 * wa.z; acc[1][3] += q1 * wa.w;
            acc[1][4] += q1 * wb.x; acc[1][5] += q1 * wb.y; acc[1][6] += q1 * wb.z; acc[1][7] += q1 * wb.w;
            acc[2][0] += q2 * wa.x; acc[2][1] += q2 * wa.y; acc[2][2] += q2 * wa.z; acc[2][3] += q2 * wa.w;
            acc[2][4] += q2 * wb.x; acc[2][5] += q2 * wb.y; acc[2][6] += q2 * wb.z; acc[2][7] += q2 * wb.w;
            acc[3][0] += q3 * wa.x; acc[3][1] += q3 * wa.y; acc[3][2] += q3 * wa.z; acc[3][3] += q3 * wa.w;
            acc[3][4] += q3 * wb.x; acc[3][5] += q3 * wb.y; acc[3][6] += q3 * wb.z; acc[3][7] += q3 * wb.w;
        }
    }

    // epilogue: p_i = sum_j tanh(acc[i][j]) * V[d]
#pragma unroll
    for (int i = 0; i < 4; ++i) {
        float p = 0.f;
#pragma unroll
        for (int j = 0; j < 8; ++j) p += tanhf(acc[i][j]) * vv[j];
        red[rg * 4 + i][cg] = p;
    }
    __syncthreads();
    if (t < ROWS) {
        float sum = 0.f;
#pragma unroll
        for (int c = 0; c < 16; ++c) sum += red[t][c];
        float x = sum + bV[0];
        float s = 1.0f / (1.0f + __expf(-x));
        if (rowBase + t < totalRows) sig[rowBase + t] = s;
    }
}

// ---------------- Kernel 2: gather + normalize + context -------------------
// One 32-lane group per (b,n); lane indexes a float4 of the 128-wide channel.
__global__ __launch_bounds__(256) void k2_gather_context(
    const float* __restrict__ values,  // (B*N, 128)
    const int*   __restrict__ neigh,   // (N, 7)
    const float* __restrict__ sig,     // (B*N)
    float* __restrict__ context,       // (B*N, 128)
    float* __restrict__ score,         // (B*N, 7)
    int Bv, int Nv)
{
    const int t    = threadIdx.x;
    const int g    = blockIdx.x * 8 + (t >> 5);   // (b,n) flat index
    const int lane = t & 31;
    const int total = Bv * Nv;
    if (g >= total) return;
    const int b = g / Nv;
    const int n = g - b * Nv;

    const int* np = neigh + (size_t)n * KNEIGH;
    const size_t rowOffB = (size_t)b * Nv;

    int   idx[KNEIGH];
    float s[KNEIGH];
    float ssum = 0.f;
#pragma unroll
    for (int k = 0; k < KNEIGH; ++k) {
        idx[k] = np[k];
        s[k]   = sig[rowOffB + idx[k]];
        ssum  += s[k];
    }
    const float inv = 1.0f / ssum;

    float4 acc = make_float4(0.f, 0.f, 0.f, 0.f);
#pragma unroll
    for (int k = 0; k < KNEIGH; ++k) {
        const float4* vp = (const float4*)(values + (rowOffB + idx[k]) * CDIM);
        float4 v4 = vp[lane];
        float a = s[k] * inv;
        acc.x += a * v4.x; acc.y += a * v4.y;
        acc.z += a * v4.z; acc.w += a * v4.w;
    }
    ((float4*)context)[(size_t)g * (CDIM / 4) + lane] = acc;

    if (lane < KNEIGH) {
        // reload to avoid dynamic register indexing (L1 hit)
        score[(size_t)g * KNEIGH + lane] = sig[rowOffB + np[lane]];
    }
}

extern "C" void kernel_launch(void* const* d_in, const int* in_sizes, int n_in,
                              void* d_out, int out_size, void* d_ws, size_t ws_size,
                              hipStream_t stream) {
    const float* query  = (const float*)d_in[0];
    const float* values = (const float*)d_in[1];
    const int*   neigh  = (const int*)d_in[2];
    const float* W1     = (const float*)d_in[3];
    const float* b1     = (const float*)d_in[4];
    const float* V      = (const float*)d_in[5];
    const float* bV     = (const float*)d_in[6];

    const int N = in_sizes[2] / KNEIGH;            // 40962
    const int totalRows = in_sizes[0] / CDIM;      // B*N
    const int B = totalRows / N;                   // 4

    float* context = (float*)d_out;                       // (B*N,128)
    float* score   = (float*)d_out + (size_t)totalRows * CDIM; // (B*N,7)
    float* sig     = (float*)d_ws;                        // (B*N) scratch

    int g1 = (totalRows + ROWS - 1) / ROWS;
    hipLaunchKernelGGL(k1_row_scores, dim3(g1), dim3(256), 0, stream,
                       query, W1, b1, V, bV, sig, totalRows);

    int g2 = (totalRows + 7) / 8;
    hipLaunchKernelGGL(k2_gather_context, dim3(g2), dim3(256), 0, stream,
                       values, neigh, sig, context, score, B, N);
}

// Round 2
// 289.173 us; speedup vs baseline: 1.1879x; 1.1879x over previous
//
#include <hip/hip_runtime.h>
#include <hip/hip_bf16.h>
#include <math.h>

// Problem: B=4, N=40962, K=7, C=128
//   sig[b,m]     = sigmoid( sum_d tanh((query[b,m,:]@W1)[d] + b1[d]) * V[d] + bV )
//   score[b,n,k] = sig[b, neigh[n,k]]
//   attn         = score / sum_k score
//   context[b,n] = sum_k attn[b,n,k] * values[b, neigh[n,k], :]

#define CDIM 128
#define KNEIGH 7
#define LDSPAD 136   // 128 + 8 bf16 pad: b128 reads -> 2-way bank alias (free)

typedef __attribute__((ext_vector_type(8))) short bf16x8;
typedef __attribute__((ext_vector_type(4))) float floatx4;

__device__ inline short f2bf(float x) {
    union { float f; unsigned u; } v; v.f = x;
    unsigned r = (v.u + 0x7fff + ((v.u >> 16) & 1)) >> 16;   // RNE
    return (short)r;
}
__device__ inline float bf2f(short h) {
    union { float f; unsigned u; } v;
    v.u = ((unsigned)(unsigned short)h) << 16; return v.f;
}
__device__ inline float fast_tanh(float x) {
    float e = __expf(2.0f * x);          // inf-safe: e=inf -> 1, e=0 -> -1
    return 1.0f - 2.0f / (e + 1.0f);
}

// ---------------- Kernel 1: per-row score precompute (MFMA) ----------------
// sig[r] for r in [0, totalRows). GEMM (rows x 128) @ W1(128x128) via
// 16x16x32 bf16 MFMA with 3-term split (qh*Wh + ql*Wh + qh*Wl) ~= fp32.
// Block 256 = 4 waves; 32 rows/wave (2 row-tiles), 128 rows/block.
__global__ __launch_bounds__(256, 2) void k1_mfma(
    const float* __restrict__ query,   // (totalRows, 128)
    const float* __restrict__ W1,      // (128, 128) [c][d]
    const float* __restrict__ b1,      // (128)
    const float* __restrict__ V,       // (128)
    const float* __restrict__ bV,      // (1)
    float* __restrict__ sig,           // (totalRows)
    int totalRows)
{
    __shared__ short Wh[CDIM][LDSPAD];   // W1^T hi plane  [d][c]
    __shared__ short Wl[CDIM][LDSPAD];   // W1^T lo plane  [d][c]

    const int t = threadIdx.x;

    // ---- stage W1 -> transposed split-bf16 LDS planes --------------------
    // thread (d = t&127, c8 = t>>7) handles c-blocks c8, c8+2, ..., c8+14.
    {
        const int d  = t & 127;
        const int c8 = t >> 7;
#pragma unroll
        for (int i = 0; i < 8; ++i) {
            const int c0 = (c8 + i * 2) * 8;
            bf16x8 hv, lv;
#pragma unroll
            for (int j = 0; j < 8; ++j) {
                float w = W1[(size_t)(c0 + j) * CDIM + d];  // coalesced over d
                short h = f2bf(w);
                hv[j] = h;
                lv[j] = f2bf(w - bf2f(h));
            }
            *(bf16x8*)&Wh[d][c0] = hv;   // 16B write, bank-friendly
            *(bf16x8*)&Wl[d][c0] = lv;
        }
    }
    __syncthreads();

    const int wv   = t >> 6;
    const int lane = t & 63;
    const int m    = lane & 15;   // MFMA row (A) / col (B,D) index
    const int q    = lane >> 4;   // quad
    const long rowBase = (long)blockIdx.x * 128 + wv * 32;

    float b1v[8], Vv[8];
#pragma unroll
    for (int t8 = 0; t8 < 8; ++t8) {
        int d = t8 * 16 + m;
        b1v[t8] = b1[d];
        Vv[t8]  = V[d];
    }

    floatx4 acc[2][8];
#pragma unroll
    for (int rt = 0; rt < 2; ++rt)
#pragma unroll
        for (int t8 = 0; t8 < 8; ++t8) acc[rt][t8] = (floatx4){0.f, 0.f, 0.f, 0.f};

#pragma unroll
    for (int ks = 0; ks < 4; ++ks) {
        const int c0 = ks * 32 + q * 8;

        bf16x8 ah[2], al[2];
#pragma unroll
        for (int rt = 0; rt < 2; ++rt) {
            long r = rowBase + rt * 16 + m;
            if (r >= totalRows) r = totalRows - 1;   // clamped rows discarded later
            const float* qp = query + r * CDIM + c0;
            float4 qa = *(const float4*)qp;
            float4 qb = *(const float4*)(qp + 4);
            float qs[8] = {qa.x, qa.y, qa.z, qa.w, qb.x, qb.y, qb.z, qb.w};
#pragma unroll
            for (int j = 0; j < 8; ++j) {
                short h = f2bf(qs[j]);
                ah[rt][j] = h;
                al[rt][j] = f2bf(qs[j] - bf2f(h));
            }
        }

#pragma unroll
        for (int t8 = 0; t8 < 8; ++t8) {
            bf16x8 bh = *(const bf16x8*)&Wh[t8 * 16 + m][c0];
            bf16x8 bl = *(const bf16x8*)&Wl[t8 * 16 + m][c0];
            acc[0][t8] = __builtin_amdgcn_mfma_f32_16x16x32_bf16(ah[0], bh, acc[0][t8], 0, 0, 0);
            acc[1][t8] = __builtin_amdgcn_mfma_f32_16x16x32_bf16(ah[1], bh, acc[1][t8], 0, 0, 0);
            acc[0][t8] = __builtin_amdgcn_mfma_f32_16x16x32_bf16(al[0], bh, acc[0][t8], 0, 0, 0);
            acc[1][t8] = __builtin_amdgcn_mfma_f32_16x16x32_bf16(al[1], bh, acc[1][t8], 0, 0, 0);
            acc[0][t8] = __builtin_amdgcn_mfma_f32_16x16x32_bf16(ah[0], bl, acc[0][t8], 0, 0, 0);
            acc[1][t8] = __builtin_amdgcn_mfma_f32_16x16x32_bf16(ah[1], bl, acc[1][t8], 0, 0, 0);
        }
    }

    // ---- epilogue: tanh, dot-V, 16-lane reduce, sigmoid ------------------
    const float bVv = bV[0];
#pragma unroll
    for (int rt = 0; rt < 2; ++rt) {
        float p[4] = {0.f, 0.f, 0.f, 0.f};
#pragma unroll
        for (int t8 = 0; t8 < 8; ++t8) {
#pragma unroll
            for (int i = 0; i < 4; ++i) {
                float x = acc[rt][t8][i] + b1v[t8];
                p[i] += fast_tanh(x) * Vv[t8];
            }
        }
#pragma unroll
        for (int mask = 1; mask <= 8; mask <<= 1) {
#pragma unroll
            for (int i = 0; i < 4; ++i) p[i] += __shfl_xor(p[i], mask, 64);
        }
        if (m == 0) {
#pragma unroll
            for (int i = 0; i < 4; ++i) {
                long r = rowBase + rt * 16 + q * 4 + i;   // D row = q*4 + reg
                if (r < totalRows)
                    sig[r] = 1.0f / (1.0f + __expf(-(p[i] + bVv)));
            }
        }
    }
}

// ---------------- Kernel 2: gather + normalize + context -------------------
// One 32-lane group per (b,n); lane indexes a float4 of the 128-wide channel.
__global__ __launch_bounds__(256) void k2_gather_context(
    const float* __restrict__ values,  // (B*N, 128)
    const int*   __restrict__ neigh,   // (N, 7)
    const float* __restrict__ sig,     // (B*N)
    float* __restrict__ context,       // (B*N, 128)
    float* __restrict__ score,         // (B*N, 7)
    int Bv, int Nv)
{
    const int t    = threadIdx.x;
    const int g    = blockIdx.x * 8 + (t >> 5);   // (b,n) flat index
    const int lane = t & 31;
    const int total = Bv * Nv;
    if (g >= total) return;
    const int b = g / Nv;
    const int n = g - b * Nv;

    const int* np = neigh + (size_t)n * KNEIGH;
    const size_t rowOffB = (size_t)b * Nv;

    int   idx[KNEIGH];
    float s[KNEIGH];
    float ssum = 0.f;
#pragma unroll
    for (int k = 0; k < KNEIGH; ++k) {
        idx[k] = np[k];
        s[k]   = sig[rowOffB + idx[k]];
        ssum  += s[k];
    }
    const float inv = 1.0f / ssum;

    floatx4 acc = (floatx4){0.f, 0.f, 0.f, 0.f};
#pragma unroll
    for (int k = 0; k < KNEIGH; ++k) {
        const floatx4* vp = (const floatx4*)(values + (rowOffB + idx[k]) * CDIM);
        floatx4 v4 = vp[lane];
        float a = s[k] * inv;
        acc += a * v4;
    }
    // nontemporal: 84MB streaming write, keep L2 for the values/sig gather
    __builtin_nontemporal_store(acc, (floatx4*)context + (size_t)g * (CDIM / 4) + lane);

    if (lane < KNEIGH) {
        float sv = sig[rowOffB + np[lane]];   // L1/L2 hit
        __builtin_nontemporal_store(sv, score + (size_t)g * KNEIGH + lane);
    }
}

extern "C" void kernel_launch(void* const* d_in, const int* in_sizes, int n_in,
                              void* d_out, int out_size, void* d_ws, size_t ws_size,
                              hipStream_t stream) {
    const float* query  = (const float*)d_in[0];
    const float* values = (const float*)d_in[1];
    const int*   neigh  = (const int*)d_in[2];
    const float* W1     = (const float*)d_in[3];
    const float* b1     = (const float*)d_in[4];
    const float* V      = (const float*)d_in[5];
    const float* bV     = (const float*)d_in[6];

    const int N = in_sizes[2] / KNEIGH;            // 40962
    const int totalRows = in_sizes[0] / CDIM;      // B*N
    const int B = totalRows / N;                   // 4

    float* context = (float*)d_out;                            // (B*N,128)
    float* score   = (float*)d_out + (size_t)totalRows * CDIM; // (B*N,7)
    float* sig     = (float*)d_ws;                             // (B*N) scratch

    int g1 = (totalRows + 127) / 128;
    hipLaunchKernelGGL(k1_mfma, dim3(g1), dim3(256), 0, stream,
                       query, W1, b1, V, bV, sig, totalRows);

    int g2 = (totalRows + 7) / 8;
    hipLaunchKernelGGL(k2_gather_context, dim3(g2), dim3(256), 0, stream,
                       values, neigh, sig, context, score, B, N);
}

// Round 3
// 282.010 us; speedup vs baseline: 1.2181x; 1.0254x over previous
//
#include <hip/hip_runtime.h>
#include <hip/hip_bf16.h>
#include <math.h>

// Problem: B=4, N=40962, K=7, C=128
//   sig[b,m]     = sigmoid( sum_d tanh((query[b,m,:]@W1)[d] + b1[d]) * V[d] + bV )
//   score[b,n,k] = sig[b, neigh[n,k]]
//   attn         = score / sum_k score
//   context[b,n] = sum_k attn[b,n,k] * values[b, neigh[n,k], :]

#define CDIM 128
#define KNEIGH 7
#define LDSPAD 136   // 128 + 8 bf16 pad: b128 reads -> 2-way bank alias (free)

typedef __attribute__((ext_vector_type(8))) short bf16x8;
typedef __attribute__((ext_vector_type(4))) short bf16x4;
typedef __attribute__((ext_vector_type(4))) float floatx4;

__device__ inline short f2bf(float x) {
    union { float f; unsigned u; } v; v.f = x;
    unsigned r = (v.u + 0x7fff + ((v.u >> 16) & 1)) >> 16;   // RNE
    return (short)r;
}
__device__ inline float bf2f(short h) {
    union { float f; unsigned u; } v;
    v.u = ((unsigned)(unsigned short)h) << 16; return v.f;
}
__device__ inline float fast_tanh(float x) {
    float e = __expf(2.0f * x);          // inf-safe: e=inf -> 1, e=0 -> -1
    return 1.0f - 2.0f / (e + 1.0f);
}

// ---------------- Kernel 1: per-row score precompute (MFMA) ----------------
// + fused values fp32->bf16 compaction tail (streaming, co-schedules with
//   other blocks' MFMA phases).
__global__ __launch_bounds__(256, 2) void k1_mfma_conv(
    const float* __restrict__ query,   // (totalRows, 128)
    const float* __restrict__ W1,      // (128, 128) [c][d]
    const float* __restrict__ b1,      // (128)
    const float* __restrict__ V,       // (128)
    const float* __restrict__ bV,      // (1)
    const float* __restrict__ values,  // (totalRows, 128)
    float* __restrict__ sig,           // (totalRows)
    short* __restrict__ vbf,           // (totalRows, 128) bf16 out (or null)
    int totalRows, int doConv)
{
    __shared__ short Wh[CDIM][LDSPAD];   // W1^T hi plane  [d][c]
    __shared__ short Wl[CDIM][LDSPAD];   // W1^T lo plane  [d][c]

    const int t = threadIdx.x;

    // ---- stage W1 -> transposed split-bf16 LDS planes --------------------
    {
        const int d  = t & 127;
        const int c8 = t >> 7;
#pragma unroll
        for (int i = 0; i < 8; ++i) {
            const int c0 = (c8 + i * 2) * 8;
            bf16x8 hv, lv;
#pragma unroll
            for (int j = 0; j < 8; ++j) {
                float w = W1[(size_t)(c0 + j) * CDIM + d];  // coalesced over d
                short h = f2bf(w);
                hv[j] = h;
                lv[j] = f2bf(w - bf2f(h));
            }
            *(bf16x8*)&Wh[d][c0] = hv;
            *(bf16x8*)&Wl[d][c0] = lv;
        }
    }
    __syncthreads();

    const int wv   = t >> 6;
    const int lane = t & 63;
    const int m    = lane & 15;   // A row / B,D col index
    const int q    = lane >> 4;   // quad
    const long rowBase = (long)blockIdx.x * 128 + wv * 32;

    float b1v[8], Vv[8];
#pragma unroll
    for (int t8 = 0; t8 < 8; ++t8) {
        int d = t8 * 16 + m;
        b1v[t8] = b1[d];
        Vv[t8]  = V[d];
    }

    floatx4 acc[2][8];
#pragma unroll
    for (int rt = 0; rt < 2; ++rt)
#pragma unroll
        for (int t8 = 0; t8 < 8; ++t8) acc[rt][t8] = (floatx4){0.f, 0.f, 0.f, 0.f};

#pragma unroll
    for (int ks = 0; ks < 4; ++ks) {
        const int c0 = ks * 32 + q * 8;

        bf16x8 ah[2], al[2];
#pragma unroll
        for (int rt = 0; rt < 2; ++rt) {
            long r = rowBase + rt * 16 + m;
            if (r >= totalRows) r = totalRows - 1;   // clamped rows discarded later
            const float* qp = query + r * CDIM + c0;
            float4 qa = *(const float4*)qp;
            float4 qb = *(const float4*)(qp + 4);
            float qs[8] = {qa.x, qa.y, qa.z, qa.w, qb.x, qb.y, qb.z, qb.w};
#pragma unroll
            for (int j = 0; j < 8; ++j) {
                short h = f2bf(qs[j]);
                ah[rt][j] = h;
                al[rt][j] = f2bf(qs[j] - bf2f(h));
            }
        }

#pragma unroll
        for (int t8 = 0; t8 < 8; ++t8) {
            bf16x8 bh = *(const bf16x8*)&Wh[t8 * 16 + m][c0];
            bf16x8 bl = *(const bf16x8*)&Wl[t8 * 16 + m][c0];
            acc[0][t8] = __builtin_amdgcn_mfma_f32_16x16x32_bf16(ah[0], bh, acc[0][t8], 0, 0, 0);
            acc[1][t8] = __builtin_amdgcn_mfma_f32_16x16x32_bf16(ah[1], bh, acc[1][t8], 0, 0, 0);
            acc[0][t8] = __builtin_amdgcn_mfma_f32_16x16x32_bf16(al[0], bh, acc[0][t8], 0, 0, 0);
            acc[1][t8] = __builtin_amdgcn_mfma_f32_16x16x32_bf16(al[1], bh, acc[1][t8], 0, 0, 0);
            acc[0][t8] = __builtin_amdgcn_mfma_f32_16x16x32_bf16(ah[0], bl, acc[0][t8], 0, 0, 0);
            acc[1][t8] = __builtin_amdgcn_mfma_f32_16x16x32_bf16(ah[1], bl, acc[1][t8], 0, 0, 0);
        }
    }

    // ---- epilogue: tanh, dot-V, 16-lane reduce, sigmoid ------------------
    const float bVv = bV[0];
#pragma unroll
    for (int rt = 0; rt < 2; ++rt) {
        float p[4] = {0.f, 0.f, 0.f, 0.f};
#pragma unroll
        for (int t8 = 0; t8 < 8; ++t8) {
#pragma unroll
            for (int i = 0; i < 4; ++i) {
                float x = acc[rt][t8][i] + b1v[t8];
                p[i] += fast_tanh(x) * Vv[t8];
            }
        }
#pragma unroll
        for (int mask = 1; mask <= 8; mask <<= 1) {
#pragma unroll
            for (int i = 0; i < 4; ++i) p[i] += __shfl_xor(p[i], mask, 64);
        }
        if (m == 0) {
#pragma unroll
            for (int i = 0; i < 4; ++i) {
                long r = rowBase + rt * 16 + q * 4 + i;   // D row = q*4 + reg
                if (r < totalRows)
                    sig[r] = 1.0f / (1.0f + __expf(-(p[i] + bVv)));
            }
        }
    }

    // ---- fused values fp32 -> bf16 compaction (grid-stride) --------------
    if (doConv) {
        const int nChunks = totalRows * (CDIM / 8);   // bf16x8 chunks
        const int stride  = gridDim.x * 256;
        for (int i = blockIdx.x * 256 + t; i < nChunks; i += stride) {
            const float4* vp = (const float4*)values + (size_t)i * 2;
            float4 a = vp[0];
            float4 b = vp[1];
            bf16x8 o;
            o[0] = f2bf(a.x); o[1] = f2bf(a.y); o[2] = f2bf(a.z); o[3] = f2bf(a.w);
            o[4] = f2bf(b.x); o[5] = f2bf(b.y); o[6] = f2bf(b.z); o[7] = f2bf(b.w);
            ((bf16x8*)vbf)[i] = o;
        }
    }
}

// ---------------- Kernel 2a: bf16 gather, XCD-batch affinity ---------------
// B=4 assumed. bid&7 = XCD (round-robin dispatch heuristic); XCD pair
// (2k,2k+1) owns batch k -> each XCD's L2 sees only one 10.7MB values slab.
__global__ __launch_bounds__(256) void k2_gather_bf16(
    const short* __restrict__ vbf,     // (B*N, 128) bf16
    const int*   __restrict__ neigh,   // (N, 7)
    const float* __restrict__ sig,     // (B*N)
    float* __restrict__ context,       // (B*N, 128)
    float* __restrict__ score,         // (B*N, 7)
    int Nv, int blocksPerBatch)
{
    const int t   = threadIdx.x;
    const int bid = blockIdx.x;
    const int xcd = bid & 7;
    const int b   = xcd >> 1;
    const int nb  = ((bid >> 3) << 1) | (xcd & 1);
    if (nb >= blocksPerBatch) return;
    const int n = nb * 8 + (t >> 5);
    if (n >= Nv) return;
    const int lane = t & 31;

    const int* np = neigh + (size_t)n * KNEIGH;
    const size_t rowOffB = (size_t)b * Nv;

    int   idx[KNEIGH];
    float s[KNEIGH];
    float ssum = 0.f;
#pragma unroll
    for (int k = 0; k < KNEIGH; ++k) {
        idx[k] = np[k];
        s[k]   = sig[rowOffB + idx[k]];
        ssum  += s[k];
    }
    const float inv = 1.0f / ssum;

    float a0 = 0.f, a1 = 0.f, a2 = 0.f, a3 = 0.f;
#pragma unroll
    for (int k = 0; k < KNEIGH; ++k) {
        const bf16x4* vp = (const bf16x4*)(vbf + (rowOffB + idx[k]) * CDIM);
        bf16x4 v4 = vp[lane];                  // 8B/lane, 256B/row contiguous
        float a = s[k] * inv;
        a0 += a * bf2f(v4[0]); a1 += a * bf2f(v4[1]);
        a2 += a * bf2f(v4[2]); a3 += a * bf2f(v4[3]);
    }
    const size_t g = rowOffB + n;
    floatx4 acc = (floatx4){a0, a1, a2, a3};
    __builtin_nontemporal_store(acc, (floatx4*)context + g * (CDIM / 4) + lane);

    if (lane < KNEIGH)
        __builtin_nontemporal_store(s[0] * 0.f + sig[rowOffB + np[lane]],
                                    score + g * KNEIGH + lane);
}

// ---------------- Kernel 2b: fp32 fallback (ws too small / B!=4) ----------
__global__ __launch_bounds__(256) void k2_gather_fp32(
    const float* __restrict__ values,
    const int*   __restrict__ neigh,
    const float* __restrict__ sig,
    float* __restrict__ context,
    float* __restrict__ score,
    int Bv, int Nv)
{
    const int t    = threadIdx.x;
    const int g    = blockIdx.x * 8 + (t >> 5);
    const int lane = t & 31;
    const int total = Bv * Nv;
    if (g >= total) return;
    const int b = g / Nv;
    const int n = g - b * Nv;

    const int* np = neigh + (size_t)n * KNEIGH;
    const size_t rowOffB = (size_t)b * Nv;

    int   idx[KNEIGH];
    float s[KNEIGH];
    float ssum = 0.f;
#pragma unroll
    for (int k = 0; k < KNEIGH; ++k) {
        idx[k] = np[k];
        s[k]   = sig[rowOffB + idx[k]];
        ssum  += s[k];
    }
    const float inv = 1.0f / ssum;

    floatx4 acc = (floatx4){0.f, 0.f, 0.f, 0.f};
#pragma unroll
    for (int k = 0; k < KNEIGH; ++k) {
        const floatx4* vp = (const floatx4*)(values + (rowOffB + idx[k]) * CDIM);
        floatx4 v4 = vp[lane];
        float a = s[k] * inv;
        acc += a * v4;
    }
    __builtin_nontemporal_store(acc, (floatx4*)context + (size_t)g * (CDIM / 4) + lane);

    if (lane < KNEIGH)
        __builtin_nontemporal_store(sig[rowOffB + np[lane]],
                                    score + (size_t)g * KNEIGH + lane);
}

extern "C" void kernel_launch(void* const* d_in, const int* in_sizes, int n_in,
                              void* d_out, int out_size, void* d_ws, size_t ws_size,
                              hipStream_t stream) {
    const float* query  = (const float*)d_in[0];
    const float* values = (const float*)d_in[1];
    const int*   neigh  = (const int*)d_in[2];
    const float* W1     = (const float*)d_in[3];
    const float* b1     = (const float*)d_in[4];
    const float* V      = (const float*)d_in[5];
    const float* bV     = (const float*)d_in[6];

    const int N = in_sizes[2] / KNEIGH;            // 40962
    const int totalRows = in_sizes[0] / CDIM;      // B*N
    const int B = totalRows / N;                   // 4

    float* context = (float*)d_out;                            // (B*N,128)
    float* score   = (float*)d_out + (size_t)totalRows * CDIM; // (B*N,7)

    float* sig = (float*)d_ws;
    size_t sigBytes = (size_t)totalRows * 4;
    size_t vbfOff   = (sigBytes + 1023) & ~(size_t)1023;
    size_t needBytes = vbfOff + (size_t)totalRows * CDIM * 2;
    const bool useBf16 = (ws_size >= needBytes) && (B == 4);
    short* vbf = (short*)((char*)d_ws + vbfOff);

    int g1 = (totalRows + 127) / 128;
    hipLaunchKernelGGL(k1_mfma_conv, dim3(g1), dim3(256), 0, stream,
                       query, W1, b1, V, bV, values, sig, vbf,
                       totalRows, useBf16 ? 1 : 0);

    if (useBf16) {
        int blocksPerBatch = (N + 7) / 8;                  // 5121
        int g2 = 8 * ((blocksPerBatch + 1) / 2);           // 20488
        hipLaunchKernelGGL(k2_gather_bf16, dim3(g2), dim3(256), 0, stream,
                           vbf, neigh, sig, context, score, N, blocksPerBatch);
    } else {
        int g2 = (totalRows + 7) / 8;
        hipLaunchKernelGGL(k2_gather_fp32, dim3(g2), dim3(256), 0, stream,
                           values, neigh, sig, context, score, B, N);
    }
}